// Round 11
// baseline (1237.652 us; speedup 1.0000x reference)
//
#include <hip/hip_runtime.h>
#include <math.h>

#define S_LEN  1024
#define BATCH  2
#define DMODEL 1024
#define NHEAD  16
#define HDIM   64
#define NLAYER 4
#define MLPD   4096
#define MROWS  (S_LEN*BATCH)   // 2048

typedef __attribute__((ext_vector_type(8))) short bf16x8_t;
typedef __attribute__((ext_vector_type(4))) float f32x4_t;

// fp32 -> bf16 round-to-nearest-even on the bit pattern
__device__ __forceinline__ unsigned short f2bf(float f) {
  union { float f; unsigned u; } c; c.f = f;
  return (unsigned short)((c.u + 0x7FFFu + ((c.u >> 16) & 1u)) >> 16);
}
__device__ __forceinline__ float bf2f(unsigned short u) {
  union { unsigned u; float f; } c; c.u = ((unsigned)u) << 16; return c.f;
}

// async global->LDS, 16B per lane. Dest must be wave-uniform base + lane*16.
__device__ __forceinline__ void gl_lds16(const unsigned short* g, unsigned short* l) {
  __builtin_amdgcn_global_load_lds(
      (const __attribute__((address_space(1))) unsigned int*)(g),
      (__attribute__((address_space(3))) unsigned int*)(l), 16, 0, 0);
}

// DPP 16-lane-row reductions (pure VALU, no DS pipe; row_ror:N = 0x120+N)
template<int CTRL>
__device__ __forceinline__ float dpp16(float x) {
  return __int_as_float(__builtin_amdgcn_update_dpp(
      0, __float_as_int(x), CTRL, 0xf, 0xf, true));
}
__device__ __forceinline__ float rowmax16(float x) {
  x = fmaxf(x, dpp16<0x128>(x));
  x = fmaxf(x, dpp16<0x124>(x));
  x = fmaxf(x, dpp16<0x122>(x));
  x = fmaxf(x, dpp16<0x121>(x));
  return x;
}
__device__ __forceinline__ float rowsum16(float x) {
  x += dpp16<0x128>(x);
  x += dpp16<0x124>(x);
  x += dpp16<0x122>(x);
  x += dpp16<0x121>(x);
  return x;
}

// ---------------------------------------------------------------------------
// fp32 -> bf16 weight conversion (grid-stride by 8 elems/thread)
// ---------------------------------------------------------------------------
__global__ __launch_bounds__(256) void w2bf_kernel(const float* __restrict__ src,
    unsigned short* __restrict__ dst, int n) {
  const int i = (blockIdx.x * 256 + threadIdx.x) * 8;
  if (i >= n) return;
  float4 v0 = *(const float4*)(src + i);
  float4 v1 = *(const float4*)(src + i + 4);
  ushort4 u0, u1;
  u0.x = f2bf(v0.x); u0.y = f2bf(v0.y); u0.z = f2bf(v0.z); u0.w = f2bf(v0.w);
  u1.x = f2bf(v1.x); u1.y = f2bf(v1.y); u1.z = f2bf(v1.z); u1.w = f2bf(v1.w);
  *(ushort4*)(dst + i)     = u0;
  *(ushort4*)(dst + i + 4) = u1;
}

// ---------------------------------------------------------------------------
// cos/sin table for RoPE: tab[s*32+j] = (cos, sin) of rot[s*32+j].
// ---------------------------------------------------------------------------
__global__ __launch_bounds__(256) void trig_kernel(const float* __restrict__ rot,
    float2* __restrict__ tab) {
  const int i = blockIdx.x * 256 + threadIdx.x;   // 32768
  const float f = rot[i];
  tab[i] = make_float2(cosf(f), sinf(f));
}

// ---------------------------------------------------------------------------
// LayerNorm over last dim (D=1024). One block (256 thr) per row.
// ---------------------------------------------------------------------------
template<bool BF16OUT>
__global__ __launch_bounds__(256) void ln_kernel(const float* __restrict__ x,
    const float* __restrict__ w, const float* __restrict__ b,
    void* __restrict__ out, float inscale) {
  const int row = blockIdx.x;
  const int tid = threadIdx.x;
  const float* xr = x + (size_t)row * DMODEL;
  float4 v = *(const float4*)(xr + tid * 4);
  v.x *= inscale; v.y *= inscale; v.z *= inscale; v.w *= inscale;
  float s1 = v.x + v.y + v.z + v.w;
  float s2 = v.x*v.x + v.y*v.y + v.z*v.z + v.w*v.w;
  #pragma unroll
  for (int off = 32; off; off >>= 1) {
    s1 += __shfl_xor(s1, off);
    s2 += __shfl_xor(s2, off);
  }
  __shared__ float as1[4], as2[4];
  if ((tid & 63) == 0) { as1[tid >> 6] = s1; as2[tid >> 6] = s2; }
  __syncthreads();
  s1 = as1[0] + as1[1] + as1[2] + as1[3];
  s2 = as2[0] + as2[1] + as2[2] + as2[3];
  const float mean = s1 * (1.0f / DMODEL);
  const float var  = s2 * (1.0f / DMODEL) - mean * mean;
  const float r = rsqrtf(var + 1e-5f);
  float4 wv = *(const float4*)(w + tid * 4);
  float4 bv = *(const float4*)(b + tid * 4);
  float o0 = (v.x - mean) * r * wv.x + bv.x;
  float o1 = (v.y - mean) * r * wv.y + bv.y;
  float o2 = (v.z - mean) * r * wv.z + bv.z;
  float o3 = (v.w - mean) * r * wv.w + bv.w;
  if (BF16OUT) {
    ushort4 u; u.x = f2bf(o0); u.y = f2bf(o1); u.z = f2bf(o2); u.w = f2bf(o3);
    *(ushort4*)((unsigned short*)out + (size_t)row * DMODEL + tid * 4) = u;
  } else {
    float4 ov; ov.x = o0; ov.y = o1; ov.z = o2; ov.w = o3;
    *(float4*)((float*)out + (size_t)row * DMODEL + tid * 4) = ov;
  }
}

// ---------------------------------------------------------------------------
// Split-K reduce + optional residual + optional fused LayerNorm.
// ---------------------------------------------------------------------------
template<int NS, bool ADDDEST, bool DOLN>
__global__ __launch_bounds__(256) void reduce_ln_kernel(
    const float* __restrict__ part, const float* __restrict__ bias,
    float* __restrict__ dest, const float* __restrict__ lnw,
    const float* __restrict__ lnb, unsigned short* __restrict__ lnout) {
  const int row = blockIdx.x;
  const int tid = threadIdx.x;
  const size_t off = (size_t)row * DMODEL + tid * 4;
  float4 v;
  if (ADDDEST) v = *(const float4*)(dest + off);
  else { v.x = 0.f; v.y = 0.f; v.z = 0.f; v.w = 0.f; }
  if (bias) {
    float4 b4 = *(const float4*)(bias + tid * 4);
    v.x += b4.x; v.y += b4.y; v.z += b4.z; v.w += b4.w;
  }
  #pragma unroll
  for (int z = 0; z < NS; ++z) {
    float4 p = *(const float4*)(part + (size_t)z * (MROWS * DMODEL) + off);
    v.x += p.x; v.y += p.y; v.z += p.z; v.w += p.w;
  }
  *(float4*)(dest + off) = v;
  if (DOLN) {
    float s1 = v.x + v.y + v.z + v.w;
    float s2 = v.x*v.x + v.y*v.y + v.z*v.z + v.w*v.w;
    #pragma unroll
    for (int o = 32; o; o >>= 1) {
      s1 += __shfl_xor(s1, o);
      s2 += __shfl_xor(s2, o);
    }
    __shared__ float as1[4], as2[4];
    if ((tid & 63) == 0) { as1[tid >> 6] = s1; as2[tid >> 6] = s2; }
    __syncthreads();
    s1 = as1[0] + as1[1] + as1[2] + as1[3];
    s2 = as2[0] + as2[1] + as2[2] + as2[3];
    const float mean = s1 * (1.0f / DMODEL);
    const float var  = s2 * (1.0f / DMODEL) - mean * mean;
    const float r = rsqrtf(var + 1e-5f);
    float4 wv = *(const float4*)(lnw + tid * 4);
    float4 bv = *(const float4*)(lnb + tid * 4);
    ushort4 u;
    u.x = f2bf((v.x - mean) * r * wv.x + bv.x);
    u.y = f2bf((v.y - mean) * r * wv.y + bv.y);
    u.z = f2bf((v.z - mean) * r * wv.z + bv.z);
    u.w = f2bf((v.w - mean) * r * wv.w + bv.w);
    *(ushort4*)(lnout + (size_t)row * DMODEL + tid * 4) = u;
  }
}

// ---------------------------------------------------------------------------
// MFMA GEMM v9 (best-measured): counted-vmcnt pipeline, 3 LDS buffers,
// depth-2 prefetch, T2 XOR-swizzle (conflicts=0), optional fused RoPE
// epilogue (qkv): rotate-half partner d^32 lives in acc[i][j^2][r].
// ---------------------------------------------------------------------------
template<int SPLIT, bool GELU, bool PARTIAL, bool OUTBF16, bool ROPE>
__global__ __launch_bounds__(256, 3) void gemm_mfma(
    const unsigned short* __restrict__ A, const unsigned short* __restrict__ W,
    const float* __restrict__ bias, void* __restrict__ Cout,
    int M, int N, int K,
    const float2* __restrict__ trig, unsigned short* __restrict__ qt,
    unsigned short* __restrict__ kt) {
  constexpr int BK = 32;
  __shared__ __align__(16) unsigned short As[3][128 * BK];
  __shared__ __align__(16) unsigned short Bs[3][128 * BK];
  const int tid  = threadIdx.x;
  const int wid  = tid >> 6;
  const int lane = tid & 63;
  const int lrow = lane & 15;
  const int lq   = lane >> 4;

  // XCD-aware swizzle (requires gridDim.x % 8 == 0)
  const int NB = gridDim.x, MB = gridDim.y;
  const int f = blockIdx.y * NB + blockIdx.x;
  const int xcd = f & 7;
  const int idx = f >> 3;
  const int m0 = (idx % MB) * 128;
  const int n0 = (xcd + (idx / MB) * 8) * 128;

  const int wm = (wid >> 1) * 64;
  const int wn = (wid & 1) * 64;
  const int Kc = K / SPLIT;
  const int kbase = blockIdx.z * Kc;
  const int nt = Kc / BK;

  f32x4_t acc[4][4];
  #pragma unroll
  for (int i = 0; i < 4; ++i)
    #pragma unroll
    for (int j = 0; j < 4; ++j) acc[i][j] = (f32x4_t){0.f, 0.f, 0.f, 0.f};

  // staging chunk c lands at LDS 16B-slot c (linear); it carries the data
  // for (row = c>>2, kc = (c&3) ^ ((row>>1)&3))  [T2 source-side swizzle]
  const int c1 = tid, c2 = tid + 256;
  const int r1c = c1 >> 2, r2c = c2 >> 2;
  const int kc1 = ((c1 & 3) ^ ((r1c >> 1) & 3)) * 8;
  const int kc2 = ((c2 & 3) ^ ((r2c >> 1) & 3)) * 8;
  const unsigned short* Ag1 = A + (size_t)(m0 + r1c) * K + kbase + kc1;
  const unsigned short* Ag2 = A + (size_t)(m0 + r2c) * K + kbase + kc2;
  const unsigned short* Wg1 = W + (size_t)(n0 + r1c) * K + kbase + kc1;
  const unsigned short* Wg2 = W + (size_t)(n0 + r2c) * K + kbase + kc2;
  const int l1 = c1 * 8, l2 = c2 * 8;

  auto stage = [&](int t, int b) {
    const int ko = t * BK;
    gl_lds16(Ag1 + ko, &As[b][l1]);
    gl_lds16(Ag2 + ko, &As[b][l2]);
    gl_lds16(Wg1 + ko, &Bs[b][l1]);
    gl_lds16(Wg2 + ko, &Bs[b][l2]);
  };
  auto compute = [&](int b) {
    bf16x8_t af[4], bfr[4];
    #pragma unroll
    for (int i = 0; i < 4; ++i) {
      const int row = wm + i * 16 + lrow;
      const int ch  = lq ^ ((row >> 1) & 3);
      af[i] = *(const bf16x8_t*)&As[b][row * BK + ch * 8];
    }
    #pragma unroll
    for (int j = 0; j < 4; ++j) {
      const int row = wn + j * 16 + lrow;
      const int ch  = lq ^ ((row >> 1) & 3);
      bfr[j] = *(const bf16x8_t*)&Bs[b][row * BK + ch * 8];
    }
    #pragma unroll
    for (int i = 0; i < 4; ++i)
      #pragma unroll
      for (int j = 0; j < 4; ++j)
        acc[i][j] = __builtin_amdgcn_mfma_f32_16x16x32_bf16(af[i], bfr[j], acc[i][j], 0, 0, 0);
  };

  // prologue: two tiles in flight
  stage(0, 0);
  stage(1, 1);

  int cr = 0;        // buffer being computed (t % 3)
  int cs = 2;        // buffer being staged ((t+2) % 3)
  for (int t = 0; t < nt - 1; ++t) {
    asm volatile("s_waitcnt vmcnt(4)" ::: "memory");  // tile t landed (per-wave)
    __builtin_amdgcn_sched_barrier(0);
    __builtin_amdgcn_s_barrier();                     // collective: buf[cr] ready
    __builtin_amdgcn_sched_barrier(0);
    if (t + 2 < nt) stage(t + 2, cs);
    compute(cr);
    cr = (cr == 2) ? 0 : cr + 1;
    cs = (cs == 2) ? 0 : cs + 1;
  }
  // last K-step: drain everything
  asm volatile("s_waitcnt vmcnt(0)" ::: "memory");
  __builtin_amdgcn_sched_barrier(0);
  __builtin_amdgcn_s_barrier();
  __builtin_amdgcn_sched_barrier(0);
  compute(cr);

  // epilogue
  float bj[4];
  #pragma unroll
  for (int j = 0; j < 4; ++j)
    bj[j] = (bias && (SPLIT == 1 || blockIdx.z == 0)) ? bias[n0 + wn + j * 16 + lrow] : 0.f;

  if (ROPE) {
    // wave-uniform: which qkv section + head for this 64-col strip
    const int strip = n0 + wn;
    const int which = strip >> 10;          // 0=q, 1=k, 2=v
    const int head  = (strip >> 6) & 15;
    #pragma unroll
    for (int i = 0; i < 4; ++i) {
      #pragma unroll
      for (int r = 0; r < 4; ++r) {
        const int row = m0 + wm + i * 16 + lq * 4 + r;   // row = s*2 + b
        const int s = row >> 1, b = row & 1;
        if (which == 2) {
          const size_t idx2 = (size_t)row * N + strip + lrow;
          #pragma unroll
          for (int j = 0; j < 4; ++j)
            ((unsigned short*)Cout)[idx2 + j * 16] = f2bf(acc[i][j][r] + bj[j]);
        } else {
          unsigned short* dst = (which == 0 ? qt : kt)
              + (((size_t)(b * 16 + head) * 1024 + s) << 6);
          #pragma unroll
          for (int j = 0; j < 4; ++j) {
            const int d = j * 16 + lrow;
            const float2 tt = trig[s * 32 + (d & 31)];
            const float sign = (j < 2) ? -1.0f : 1.0f;
            const float val = acc[i][j][r] + bj[j];
            const float par = acc[i][j ^ 2][r] + bj[j ^ 2];
            dst[d] = f2bf(val * tt.x + sign * par * tt.y);
          }
        }
      }
    }
  } else {
    // C/D layout col=lane&15, row=(lane>>4)*4+r
    const size_t zoff = PARTIAL ? (size_t)blockIdx.z * ((size_t)M * N) : 0;
    #pragma unroll
    for (int i = 0; i < 4; ++i) {
      #pragma unroll
      for (int r = 0; r < 4; ++r) {
        const int row = m0 + wm + i * 16 + lq * 4 + r;
        const size_t idx2 = (size_t)row * N + n0 + wn + lrow;
        #pragma unroll
        for (int j = 0; j < 4; ++j) {
          float val = acc[i][j][r] + bj[j];
          if (GELU)
            val = 0.5f * val * (1.0f + erff(val * 0.70710678118654752f));
          if (PARTIAL)
            ((float*)Cout)[zoff + idx2 + j * 16] = val;
          else if (OUTBF16)
            ((unsigned short*)Cout)[idx2 + j * 16] = f2bf(val);
          else
            ((float*)Cout)[idx2 + j * 16] = val;
        }
      }
    }
  }
}

// ---------------------------------------------------------------------------
// V transpose via LDS tile: qkv v-part (s-major) -> vt (B,H,64,S) d-major.
// ---------------------------------------------------------------------------
__global__ __launch_bounds__(256) void vtrans_kernel(const unsigned short* __restrict__ qkv,
    unsigned short* __restrict__ vt) {
  const int bh = blockIdx.x >> 4;
  const int s0 = (blockIdx.x & 15) * 64;
  const int b = bh >> 4, hh = bh & 15;
  __shared__ unsigned short Vl[64 * 72];
  const int t = threadIdx.x;
  const int sl = t >> 2, dcol = (t & 3) * 16;
  const unsigned short* src = qkv + (size_t)((s0 + sl) * 2 + b) * 3072 + 2048 + hh * 64 + dcol;
  uint4 a = *(const uint4*)(src);
  uint4 c = *(const uint4*)(src + 8);
  *(uint4*)&Vl[sl * 72 + dcol]     = a;
  *(uint4*)&Vl[sl * 72 + dcol + 8] = c;
  __syncthreads();
  const int dr = t >> 2, soff = (t & 3) * 16;
  unsigned short o[16];
  #pragma unroll
  for (int i = 0; i < 16; ++i) o[i] = Vl[(soff + i) * 72 + dr];
  unsigned short* dst = vt + (((size_t)bh * 64 + dr) << 10) + s0 + soff;
  *(uint4*)(dst)     = *(uint4*)(o);
  *(uint4*)(dst + 8) = *(uint4*)(o + 8);
}

// ---------------------------------------------------------------------------
// MFMA flash attention v2: 2-wave blocks, 32 queries each, full KV loop.
// Grid 1024 = 4 blocks/CU (was 2) — doubles independent barrier-groups to
// hide the per-tile dependent chain. No merge kernel; K/V re-reads are
// L2-resident (256KB/bh). T14 async-STAGE + DPP reductions + skip-rescale.
// ---------------------------------------------------------------------------
__global__ __launch_bounds__(128, 2) void attn_kernel(
    const unsigned short* __restrict__ q, const unsigned short* __restrict__ k,
    const unsigned short* __restrict__ vtr, unsigned short* __restrict__ o) {
  const int tid  = threadIdx.x;
  const int wid  = tid >> 6;          // 0..1
  const int lane = tid & 63;
  const int col  = lane & 15;
  const int quad = lane >> 4;
  const int bh   = blockIdx.x >> 5;
  const int qw   = (blockIdx.x & 31) * 32 + wid * 16;

  __shared__ __align__(16) unsigned short Ks[64 * 72];
  __shared__ __align__(16) unsigned short Vs[64 * 72];
  __shared__ __align__(16) unsigned short Pl_[2][16 * 72];
  unsigned short* Pl = Pl_[wid];

  const unsigned short* kb = k   + ((size_t)bh << 16);
  const unsigned short* vb = vtr + ((size_t)bh << 16);

  bf16x8_t qa0, qa1;
  {
    const unsigned short* qp = q + ((((size_t)bh << 10) + qw + col) << 6) + quad * 8;
    qa0 = *(const bf16x8_t*)(qp);
    qa1 = *(const bf16x8_t*)(qp + 32);
  }

  f32x4_t oacc[4];
  #pragma unroll
  for (int j = 0; j < 4; ++j) oacc[j] = (f32x4_t){0.f, 0.f, 0.f, 0.f};
  float mr[4] = {-3.0e38f, -3.0e38f, -3.0e38f, -3.0e38f};
  float lr[4] = {0.f, 0.f, 0.f, 0.f};

  // staging with 128 threads: thread covers 64B (4 x 16B) of K and V
  const int srow = tid >> 1;              // 0..63
  const int scol = (tid & 1) * 32;        // 0 or 32 (shorts)
  const unsigned short* gk0 = kb + (size_t)srow * 64 + scol;
  const unsigned short* gv0 = vb + (size_t)srow * 1024 + scol;
  unsigned short* lk0 = &Ks[srow * 72 + scol];
  unsigned short* lv0 = &Vs[srow * 72 + scol];

  // prologue: stage tile 0
  {
    #pragma unroll
    for (int c = 0; c < 4; ++c) {
      *(uint4*)(lk0 + c * 8) = *(const uint4*)(gk0 + c * 8);
      *(uint4*)(lv0 + c * 8) = *(const uint4*)(gv0 + c * 8);
    }
  }
  __syncthreads();

  for (int t0 = 0; t0 < 1024; t0 += 64) {
    // T14 issue-early: next tile's loads go in flight during compute
    const bool more = (t0 + 64) < 1024;
    uint4 nk[4], nv[4];
    if (more) {
      const unsigned short* gk = gk0 + (size_t)(t0 + 64) * 64;
      const unsigned short* gv = gv0 + (t0 + 64);
      #pragma unroll
      for (int c = 0; c < 4; ++c) {
        nk[c] = *(const uint4*)(gk + c * 8);
        nv[c] = *(const uint4*)(gv + c * 8);
      }
    }

    f32x4_t sc[4];
    #pragma unroll
    for (int j = 0; j < 4; ++j) {
      bf16x8_t kf0 = *(const bf16x8_t*)&Ks[(j * 16 + col) * 72 + quad * 8];
      bf16x8_t kf1 = *(const bf16x8_t*)&Ks[(j * 16 + col) * 72 + quad * 8 + 32];
      f32x4_t c = (f32x4_t){0.f, 0.f, 0.f, 0.f};
      c = __builtin_amdgcn_mfma_f32_16x16x32_bf16(qa0, kf0, c, 0, 0, 0);
      c = __builtin_amdgcn_mfma_f32_16x16x32_bf16(qa1, kf1, c, 0, 0, 0);
      sc[j] = c;
    }

    #pragma unroll
    for (int r = 0; r < 4; ++r) {
      float s0 = sc[0][r] * 0.125f, s1 = sc[1][r] * 0.125f;
      float s2 = sc[2][r] * 0.125f, s3 = sc[3][r] * 0.125f;
      const float rm = rowmax16(fmaxf(fmaxf(s0, s1), fmaxf(s2, s3)));
      if (__any(rm > mr[r])) {              // exact: alpha==1 when skipped
        const float mn = fmaxf(mr[r], rm);
        const float alpha = __expf(mr[r] - mn);
        mr[r] = mn;
        lr[r] *= alpha;
        #pragma unroll
        for (int j = 0; j < 4; ++j) oacc[j][r] *= alpha;
      }
      const float m = mr[r];
      const float p0 = __expf(s0 - m), p1 = __expf(s1 - m);
      const float p2 = __expf(s2 - m), p3 = __expf(s3 - m);
      lr[r] += rowsum16(p0 + p1 + p2 + p3);
      const int prow = (quad * 4 + r) * 72;
      Pl[prow +  0 + col] = f2bf(p0);
      Pl[prow + 16 + col] = f2bf(p1);
      Pl[prow + 32 + col] = f2bf(p2);
      Pl[prow + 48 + col] = f2bf(p3);
    }

    bf16x8_t pa0 = *(const bf16x8_t*)&Pl[col * 72 + quad * 8];
    bf16x8_t pa1 = *(const bf16x8_t*)&Pl[col * 72 + quad * 8 + 32];
    #pragma unroll
    for (int j = 0; j < 4; ++j) {
      bf16x8_t vf0 = *(const bf16x8_t*)&Vs[(j * 16 + col) * 72 + quad * 8];
      bf16x8_t vf1 = *(const bf16x8_t*)&Vs[(j * 16 + col) * 72 + quad * 8 + 32];
      oacc[j] = __builtin_amdgcn_mfma_f32_16x16x32_bf16(pa0, vf0, oacc[j], 0, 0, 0);
      oacc[j] = __builtin_amdgcn_mfma_f32_16x16x32_bf16(pa1, vf1, oacc[j], 0, 0, 0);
    }

    // write-late: all waves done reading Ks/Vs, then land the staged regs
    __syncthreads();
    if (more) {
      #pragma unroll
      for (int c = 0; c < 4; ++c) {
        *(uint4*)(lk0 + c * 8) = nk[c];
        *(uint4*)(lv0 + c * 8) = nv[c];
      }
    }
    __syncthreads();
  }

  const int b = bh >> 4, hh = bh & 15;
  #pragma unroll
  for (int r = 0; r < 4; ++r) {
    const float inv = 1.0f / lr[r];
    const int sq = qw + quad * 4 + r;
    unsigned short* orow = o + (((size_t)sq * 2 + b) << 10) + hh * 64;
    #pragma unroll
    for (int j = 0; j < 4; ++j)
      orow[j * 16 + col] = f2bf(oacc[j][r] * inv);
  }
}

// ---------------------------------------------------------------------------
// Mean over tokens: tsum[b,d] += sum_s h[s,b,d] (8 s-chunks, atomicAdd).
// ---------------------------------------------------------------------------
__global__ __launch_bounds__(256) void mean_kernel(const float* __restrict__ h,
    float* __restrict__ tsum) {
  const int idx = blockIdx.x * 256 + threadIdx.x;
  const int bd = idx & 2047;
  const int sc = idx >> 11;
  const int b = bd >> 10, d = bd & 1023;
  float sm = 0.f;
  for (int s = sc * 128; s < sc * 128 + 128; ++s)
    sm += h[(((size_t)s * 2 + b) << 10) + d];
  atomicAdd(&tsum[bd], sm);
}

// ---------------------------------------------------------------------------
// Small mat-vec: out[b,n] = sum_d in[b,d]*W[n,d] (+bias). Wave per output n.
// ---------------------------------------------------------------------------
__global__ __launch_bounds__(256) void smallmv_kernel(const float* __restrict__ in,
    const float* __restrict__ W, const float* __restrict__ bias,
    float* __restrict__ out) {
  const int lane = threadIdx.x & 63;
  const int n = blockIdx.x * 4 + (threadIdx.x >> 6);
  const int b = blockIdx.y;
  const float* wr = W + (size_t)n * 1024;
  const float* xr = in + (size_t)b * 1024;
  float sm = 0.f;
  #pragma unroll
  for (int j = 0; j < 4; ++j) {
    float4 wv = *(const float4*)(wr + lane * 4 + j * 256);
    float4 xv = *(const float4*)(xr + lane * 4 + j * 256);
    sm += wv.x * xv.x + wv.y * xv.y + wv.z * xv.z + wv.w * xv.w;
  }
  #pragma unroll
  for (int off = 32; off; off >>= 1) sm += __shfl_xor(sm, off);
  if (lane == 0) out[(size_t)b * 1024 + n] = sm + (bias ? bias[n] : 0.f);
}

// ---------------------------------------------------------------------------
// Pooling cross-attention, split-K: 512 waves, each (bh, 64-key block).
// ---------------------------------------------------------------------------
__global__ __launch_bounds__(256) void pool_attn_part(const float* __restrict__ q,
    const float* __restrict__ k, const float* __restrict__ v,
    float* __restrict__ part) {
  const int wid  = (blockIdx.x * 256 + threadIdx.x) >> 6;  // 0..511
  const int lane = threadIdx.x & 63;
  const int bh = wid >> 4, kblk = wid & 15;
  const int b = bh >> 4, hh = bh & 15;
  const float qd = q[(size_t)b * 1024 + hh * 64 + lane];
  float mx = -3.0e38f, l = 0.f, acc = 0.f;
  for (int t = kblk * 64; t < kblk * 64 + 64; ++t) {
    const size_t ro = (((size_t)t * 2 + b) << 10) + hh * 64 + lane;
    float p = qd * k[ro];
    p += __shfl_xor(p, 32); p += __shfl_xor(p, 16); p += __shfl_xor(p, 8);
    p += __shfl_xor(p, 4);  p += __shfl_xor(p, 2);  p += __shfl_xor(p, 1);
    const float sc = p * 0.125f;
    const float mn = fmaxf(mx, sc);
    const float alpha = __expf(mx - mn);
    const float w = __expf(sc - mn);
    acc = acc * alpha + w * v[ro];
    l   = l * alpha + w;
    mx  = mn;
  }
  float* pp = part + (size_t)wid * 68;
  if (lane == 0) { pp[0] = mx; pp[1] = l; }
  pp[4 + lane] = acc;
}

__global__ __launch_bounds__(256) void pool_attn_comb(const float* __restrict__ part,
    float* __restrict__ o) {
  const int wid  = (blockIdx.x * 256 + threadIdx.x) >> 6;  // 0..31 = bh
  const int lane = threadIdx.x & 63;
  const float* pb = part + (size_t)wid * 16 * 68;
  float M = -3.0e38f;
  #pragma unroll
  for (int w = 0; w < 16; ++w) M = fmaxf(M, pb[w * 68]);
  float L = 0.f, O = 0.f;
  #pragma unroll
  for (int w = 0; w < 16; ++w) {
    const float e = __expf(pb[w * 68] - M);
    L += e * pb[w * 68 + 1];
    O += e * pb[w * 68 + 4 + lane];
  }
  const int b = wid >> 4, hh = wid & 15;
  o[(size_t)b * 1024 + hh * 64 + lane] = O / L;
}

// ---------------------------------------------------------------------------
extern "C" void kernel_launch(void* const* d_in, const int* in_sizes, int n_in,
                              void* d_out, int out_size, void* d_ws, size_t ws_size,
                              hipStream_t stream) {
  (void)in_sizes; (void)n_in; (void)out_size; (void)ws_size;
  const float* x     = (const float*)d_in[0];
  const float* rot   = (const float*)d_in[1];
  const float* ln1_w = (const float*)d_in[2];
  const float* ln1_b = (const float*)d_in[3];
  const float* in_w  = (const float*)d_in[4];
  const float* in_b  = (const float*)d_in[5];
  const float* out_w = (const float*)d_in[6];
  const float* out_b = (const float*)d_in[7];
  const float* ln2_w = (const float*)d_in[8];
  const float* ln2_b = (const float*)d_in[9];
  const float* fc_w  = (const float*)d_in[10];
  const float* fc_b  = (const float*)d_in[11];
  const float* cp_w  = (const float*)d_in[12];
  const float* cp_b  = (const float*)d_in[13];
  const float* pn_q_w = (const float*)d_in[14];
  const float* pn_q_b = (const float*)d_in[15];
  const float* pn_k_w = (const float*)d_in[16];
  const float* pn_k_b = (const float*)d_in[17];
  const float* pn_v_w = (const float*)d_in[18];
  const float* pn_v_b = (const float*)d_in[19];
  const float* pq_w  = (const float*)d_in[20];
  const float* pk_w  = (const float*)d_in[21];
  const float* pv_w  = (const float*)d_in[22];
  const float* pp_w  = (const float*)d_in[23];
  const float* pp_b  = (const float*)d_in[24];

  float* ws = (float*)d_ws;
  const size_t M1 = 1u << 20;
  float* h  = ws;              // 2M fl  (S,B,D) residual stream fp32
  float* a  = ws + 2 * M1;     // LN out bf16 / xk bf16
  float* r1 = ws + 4 * M1;     // qkv(v) bf16 / mlp bf16 / xv bf16; out-proj partials
  float* qt = ws + 12 * M1;    // q bf16 (B,H,S,64)  | c_proj partials | pooling scratch
  float* kt = ws + 14 * M1;    // k bf16 (B,H,S,64)  | k_pool fp32
  float* vt = ws + 16 * M1;    // v^T bf16 (B,H,64,S)| v_pool fp32
  float* o  = ws + 18 * M1;    // attn out bf16 (S,B,D)
  float* trig = ws + 19 * M1;  // 32K float2 cos/sin table (64K floats)
  float* wbf = ws + 20 * M1;   // bf16 weights, ALL layers
  unsigned short* a_bf  = (unsigned short*)a;
  unsigned short* r1_bf = (unsigned short*)r1;
  unsigned short* o_bf  = (unsigned short*)o;
  unsigned short* qt_bf = (unsigned short*)qt;
  unsigned short* kt_bf = (unsigned short*)kt;
  unsigned short* vt_bf = (unsigned short*)vt;
  // bf16 weight partitions, all 4 layers (ushort elems)
  unsigned short* wb_qkv_all = (unsigned short*)wbf;        // 12,582,912
  unsigned short* wb_out_all = wb_qkv_all + 12582912;       //  4,194,304
  unsigned short* wb_fc_all  = wb_out_all + 4194304;        // 16,777,216
  unsigned short* wb_cp_all  = wb_fc_all  + 16777216;       // 16,777,216
  // split-K partial buffers (fp32, slice stride MROWS*DMODEL = 2M floats)
  float* part_op = r1;            // out-proj partials (4 x 2M1)
  float* part_cp = qt;            // c_proj partials (4 x 2M1)
  float* part_pool = ws + 5 * M1; // pool partials SPLIT=2 (2 x 2M1)
  float* tsum  = qt;              // pooling scratch reuses qt region
  float* xq    = qt + 2048;
  float* qpool = qt + 4096;
  float* opool = qt + 6144;
  float* ppart = qt + 8192;       // 512*68 floats

  hipMemcpyAsync(h, x, 2 * M1 * sizeof(float), hipMemcpyDeviceToDevice, stream);

  // one-time setup: trig table, ln1 for layer 0, ALL weight conversions
  trig_kernel<<<128, 256, 0, stream>>>(rot, (float2*)trig);
  ln_kernel<true><<<MROWS, 256, 0, stream>>>(h, ln1_w, ln1_b, a_bf, 1.0f);
  w2bf_kernel<<<12582912 / 2048, 256, 0, stream>>>(in_w,  wb_qkv_all, 12582912);
  w2bf_kernel<<<4194304  / 2048, 256, 0, stream>>>(out_w, wb_out_all, 4194304);
  w2bf_kernel<<<16777216 / 2048, 256, 0, stream>>>(fc_w,  wb_fc_all,  16777216);
  w2bf_kernel<<<16777216 / 2048, 256, 0, stream>>>(cp_w,  wb_cp_all,  16777216);

  for (int l = 0; l < NLAYER; ++l) {
    const unsigned short* wb_qkv = wb_qkv_all + (size_t)l * 3145728;
    const unsigned short* wb_out = wb_out_all + (size_t)l * 1048576;
    const unsigned short* wb_fc  = wb_fc_all  + (size_t)l * 4194304;
    const unsigned short* wb_cp  = wb_cp_all  + (size_t)l * 4194304;

    // QKV with FUSED RoPE epilogue: q/k -> qt/kt (rotated), v -> r1
    gemm_mfma<1, false, false, true, true><<<dim3(3072 / 128, MROWS / 128, 1), 256, 0, stream>>>(
        a_bf, wb_qkv, in_b + l * 3072, r1_bf, MROWS, 3072, 1024,
        (const float2*)trig, qt_bf, kt_bf);
    vtrans_kernel<<<512, 256, 0, stream>>>(r1_bf, vt_bf);
    attn_kernel<<<1024, 128, 0, stream>>>(qt_bf, kt_bf, vt_bf, o_bf);
    // out-proj: SPLIT=4 partials (no atomics), then reduce + residual + ln2
    gemm_mfma<4, false, true, false, false><<<dim3(1024 / 128, MROWS / 128, 4), 256, 0, stream>>>(
        o_bf, wb_out, nullptr, part_op, MROWS, 1024, 1024, nullptr, nullptr, nullptr);
    reduce_ln_kernel<4, true, true><<<MROWS, 256, 0, stream>>>(
        part_op, out_b + l * 1024, h, ln2_w + l * DMODEL, ln2_b + l * DMODEL, a_bf);
    // FC + GELU: SPLIT=1, bf16 out
    gemm_mfma<1, true, false, true, false><<<dim3(4096 / 128, MROWS / 128, 1), 256, 0, stream>>>(
        a_bf, wb_fc, fc_b + l * 4096, r1_bf, MROWS, 4096, 1024, nullptr, nullptr, nullptr);
    // c_proj: SPLIT=4 partials, then reduce + residual + next layer's ln1
    gemm_mfma<4, false, true, false, false><<<dim3(1024 / 128, MROWS / 128, 4), 256, 0, stream>>>(
        r1_bf, wb_cp, nullptr, part_cp, MROWS, 1024, 4096, nullptr, nullptr, nullptr);
    if (l < NLAYER - 1)
      reduce_ln_kernel<4, true, true><<<MROWS, 256, 0, stream>>>(
          part_cp, cp_b + l * 1024, h,
          ln1_w + (l + 1) * DMODEL, ln1_b + (l + 1) * DMODEL, a_bf);
    else
      reduce_ln_kernel<4, true, false><<<MROWS, 256, 0, stream>>>(
          part_cp, cp_b + l * 1024, h, nullptr, nullptr, nullptr);
  }

  // ---- attention pooling head ----
  hipMemsetAsync(tsum, 0, 2048 * sizeof(float), stream);
  mean_kernel<<<64, 256, 0, stream>>>(h, tsum);
  ln_kernel<false><<<BATCH, 256, 0, stream>>>(tsum, pn_q_w, pn_q_b, xq, 1.0f / S_LEN);
  ln_kernel<true><<<MROWS, 256, 0, stream>>>(h, pn_k_w, pn_k_b, a_bf, 1.0f);    // xk bf16
  ln_kernel<true><<<MROWS, 256, 0, stream>>>(h, pn_v_w, pn_v_b, r1_bf, 1.0f);   // xv bf16
  smallmv_kernel<<<dim3(256, BATCH), 256, 0, stream>>>(xq, pq_w, nullptr, qpool);
  // pool k/v projections: bf16 weights (reuse weight region), SPLIT=2 partials
  unsigned short* wb_pk = wb_qkv_all;
  unsigned short* wb_pv = wb_qkv_all + 1048576;
  w2bf_kernel<<<1048576 / 2048, 256, 0, stream>>>(pk_w, wb_pk, 1048576);
  w2bf_kernel<<<1048576 / 2048, 256, 0, stream>>>(pv_w, wb_pv, 1048576);
  gemm_mfma<2, false, true, false, false><<<dim3(1024 / 128, MROWS / 128, 2), 256, 0, stream>>>(
      a_bf, wb_pk, nullptr, part_pool, MROWS, 1024, 1024, nullptr, nullptr, nullptr);
  reduce_ln_kernel<2, false, false><<<MROWS, 256, 0, stream>>>(
      part_pool, nullptr, kt, nullptr, nullptr, nullptr);   // k_pool fp32
  gemm_mfma<2, false, true, false, false><<<dim3(1024 / 128, MROWS / 128, 2), 256, 0, stream>>>(
      r1_bf, wb_pv, nullptr, part_pool, MROWS, 1024, 1024, nullptr, nullptr, nullptr);
  reduce_ln_kernel<2, false, false><<<MROWS, 256, 0, stream>>>(
      part_pool, nullptr, vt, nullptr, nullptr, nullptr);   // v_pool fp32
  pool_attn_part<<<128, 256, 0, stream>>>(qpool, kt, vt, ppart);
  pool_attn_comb<<<8, 256, 0, stream>>>(ppart, opool);
  smallmv_kernel<<<dim3(256, BATCH), 256, 0, stream>>>(opool, pp_w, pp_b, (float*)d_out);
}

// Round 12
// 1025.796 us; speedup vs baseline: 1.2065x; 1.2065x over previous
//
#include <hip/hip_runtime.h>
#include <math.h>

#define S_LEN  1024
#define BATCH  2
#define DMODEL 1024
#define NHEAD  16
#define HDIM   64
#define NLAYER 4
#define MLPD   4096
#define MROWS  (S_LEN*BATCH)   // 2048

typedef __attribute__((ext_vector_type(8))) short bf16x8_t;
typedef __attribute__((ext_vector_type(4))) float f32x4_t;

// fp32 -> bf16 round-to-nearest-even on the bit pattern
__device__ __forceinline__ unsigned short f2bf(float f) {
  union { float f; unsigned u; } c; c.f = f;
  return (unsigned short)((c.u + 0x7FFFu + ((c.u >> 16) & 1u)) >> 16);
}
__device__ __forceinline__ float bf2f(unsigned short u) {
  union { unsigned u; float f; } c; c.u = ((unsigned)u) << 16; return c.f;
}

// async global->LDS, 16B per lane. Dest must be wave-uniform base + lane*16.
__device__ __forceinline__ void gl_lds16(const unsigned short* g, unsigned short* l) {
  __builtin_amdgcn_global_load_lds(
      (const __attribute__((address_space(1))) unsigned int*)(g),
      (__attribute__((address_space(3))) unsigned int*)(l), 16, 0, 0);
}

// DPP 16-lane-row reductions (pure VALU, no DS pipe; row_ror:N = 0x120+N)
template<int CTRL>
__device__ __forceinline__ float dpp16(float x) {
  return __int_as_float(__builtin_amdgcn_update_dpp(
      0, __float_as_int(x), CTRL, 0xf, 0xf, true));
}
__device__ __forceinline__ float rowmax16(float x) {
  x = fmaxf(x, dpp16<0x128>(x));
  x = fmaxf(x, dpp16<0x124>(x));
  x = fmaxf(x, dpp16<0x122>(x));
  x = fmaxf(x, dpp16<0x121>(x));
  return x;
}
__device__ __forceinline__ float rowsum16(float x) {
  x += dpp16<0x128>(x);
  x += dpp16<0x124>(x);
  x += dpp16<0x122>(x);
  x += dpp16<0x121>(x);
  return x;
}

// ---------------------------------------------------------------------------
// fp32 -> bf16 weight conversion (grid-stride by 8 elems/thread)
// ---------------------------------------------------------------------------
__global__ __launch_bounds__(256) void w2bf_kernel(const float* __restrict__ src,
    unsigned short* __restrict__ dst, int n) {
  const int i = (blockIdx.x * 256 + threadIdx.x) * 8;
  if (i >= n) return;
  float4 v0 = *(const float4*)(src + i);
  float4 v1 = *(const float4*)(src + i + 4);
  ushort4 u0, u1;
  u0.x = f2bf(v0.x); u0.y = f2bf(v0.y); u0.z = f2bf(v0.z); u0.w = f2bf(v0.w);
  u1.x = f2bf(v1.x); u1.y = f2bf(v1.y); u1.z = f2bf(v1.z); u1.w = f2bf(v1.w);
  *(ushort4*)(dst + i)     = u0;
  *(ushort4*)(dst + i + 4) = u1;
}

// ---------------------------------------------------------------------------
// cos/sin table for RoPE: tab[s*32+j] = (cos, sin) of rot[s*32+j].
// ---------------------------------------------------------------------------
__global__ __launch_bounds__(256) void trig_kernel(const float* __restrict__ rot,
    float2* __restrict__ tab) {
  const int i = blockIdx.x * 256 + threadIdx.x;   // 32768
  const float f = rot[i];
  tab[i] = make_float2(cosf(f), sinf(f));
}

// ---------------------------------------------------------------------------
// LayerNorm over last dim (D=1024). One block (256 thr) per row.
// ---------------------------------------------------------------------------
template<bool BF16OUT>
__global__ __launch_bounds__(256) void ln_kernel(const float* __restrict__ x,
    const float* __restrict__ w, const float* __restrict__ b,
    void* __restrict__ out, float inscale) {
  const int row = blockIdx.x;
  const int tid = threadIdx.x;
  const float* xr = x + (size_t)row * DMODEL;
  float4 v = *(const float4*)(xr + tid * 4);
  v.x *= inscale; v.y *= inscale; v.z *= inscale; v.w *= inscale;
  float s1 = v.x + v.y + v.z + v.w;
  float s2 = v.x*v.x + v.y*v.y + v.z*v.z + v.w*v.w;
  #pragma unroll
  for (int off = 32; off; off >>= 1) {
    s1 += __shfl_xor(s1, off);
    s2 += __shfl_xor(s2, off);
  }
  __shared__ float as1[4], as2[4];
  if ((tid & 63) == 0) { as1[tid >> 6] = s1; as2[tid >> 6] = s2; }
  __syncthreads();
  s1 = as1[0] + as1[1] + as1[2] + as1[3];
  s2 = as2[0] + as2[1] + as2[2] + as2[3];
  const float mean = s1 * (1.0f / DMODEL);
  const float var  = s2 * (1.0f / DMODEL) - mean * mean;
  const float r = rsqrtf(var + 1e-5f);
  float4 wv = *(const float4*)(w + tid * 4);
  float4 bv = *(const float4*)(b + tid * 4);
  float o0 = (v.x - mean) * r * wv.x + bv.x;
  float o1 = (v.y - mean) * r * wv.y + bv.y;
  float o2 = (v.z - mean) * r * wv.z + bv.z;
  float o3 = (v.w - mean) * r * wv.w + bv.w;
  if (BF16OUT) {
    ushort4 u; u.x = f2bf(o0); u.y = f2bf(o1); u.z = f2bf(o2); u.w = f2bf(o3);
    *(ushort4*)((unsigned short*)out + (size_t)row * DMODEL + tid * 4) = u;
  } else {
    float4 ov; ov.x = o0; ov.y = o1; ov.z = o2; ov.w = o3;
    *(float4*)((float*)out + (size_t)row * DMODEL + tid * 4) = ov;
  }
}

// ---------------------------------------------------------------------------
// Split-K reduce + optional residual + optional fused LayerNorm.
// ---------------------------------------------------------------------------
template<int NS, bool ADDDEST, bool DOLN>
__global__ __launch_bounds__(256) void reduce_ln_kernel(
    const float* __restrict__ part, const float* __restrict__ bias,
    float* __restrict__ dest, const float* __restrict__ lnw,
    const float* __restrict__ lnb, unsigned short* __restrict__ lnout) {
  const int row = blockIdx.x;
  const int tid = threadIdx.x;
  const size_t off = (size_t)row * DMODEL + tid * 4;
  float4 v;
  if (ADDDEST) v = *(const float4*)(dest + off);
  else { v.x = 0.f; v.y = 0.f; v.z = 0.f; v.w = 0.f; }
  if (bias) {
    float4 b4 = *(const float4*)(bias + tid * 4);
    v.x += b4.x; v.y += b4.y; v.z += b4.z; v.w += b4.w;
  }
  #pragma unroll
  for (int z = 0; z < NS; ++z) {
    float4 p = *(const float4*)(part + (size_t)z * (MROWS * DMODEL) + off);
    v.x += p.x; v.y += p.y; v.z += p.z; v.w += p.w;
  }
  *(float4*)(dest + off) = v;
  if (DOLN) {
    float s1 = v.x + v.y + v.z + v.w;
    float s2 = v.x*v.x + v.y*v.y + v.z*v.z + v.w*v.w;
    #pragma unroll
    for (int o = 32; o; o >>= 1) {
      s1 += __shfl_xor(s1, o);
      s2 += __shfl_xor(s2, o);
    }
    __shared__ float as1[4], as2[4];
    if ((tid & 63) == 0) { as1[tid >> 6] = s1; as2[tid >> 6] = s2; }
    __syncthreads();
    s1 = as1[0] + as1[1] + as1[2] + as1[3];
    s2 = as2[0] + as2[1] + as2[2] + as2[3];
    const float mean = s1 * (1.0f / DMODEL);
    const float var  = s2 * (1.0f / DMODEL) - mean * mean;
    const float r = rsqrtf(var + 1e-5f);
    float4 wv = *(const float4*)(lnw + tid * 4);
    float4 bv = *(const float4*)(lnb + tid * 4);
    ushort4 u;
    u.x = f2bf((v.x - mean) * r * wv.x + bv.x);
    u.y = f2bf((v.y - mean) * r * wv.y + bv.y);
    u.z = f2bf((v.z - mean) * r * wv.z + bv.z);
    u.w = f2bf((v.w - mean) * r * wv.w + bv.w);
    *(ushort4*)(lnout + (size_t)row * DMODEL + tid * 4) = u;
  }
}

// ---------------------------------------------------------------------------
// MFMA GEMM v9 (best-measured): counted-vmcnt pipeline, 3 LDS buffers,
// depth-2 prefetch, T2 XOR-swizzle (conflicts=0), optional fused RoPE
// epilogue (qkv): rotate-half partner d^32 lives in acc[i][j^2][r].
// ---------------------------------------------------------------------------
template<int SPLIT, bool GELU, bool PARTIAL, bool OUTBF16, bool ROPE>
__global__ __launch_bounds__(256, 3) void gemm_mfma(
    const unsigned short* __restrict__ A, const unsigned short* __restrict__ W,
    const float* __restrict__ bias, void* __restrict__ Cout,
    int M, int N, int K,
    const float2* __restrict__ trig, unsigned short* __restrict__ qt,
    unsigned short* __restrict__ kt) {
  constexpr int BK = 32;
  __shared__ __align__(16) unsigned short As[3][128 * BK];
  __shared__ __align__(16) unsigned short Bs[3][128 * BK];
  const int tid  = threadIdx.x;
  const int wid  = tid >> 6;
  const int lane = tid & 63;
  const int lrow = lane & 15;
  const int lq   = lane >> 4;

  // XCD-aware swizzle (requires gridDim.x % 8 == 0)
  const int NB = gridDim.x, MB = gridDim.y;
  const int f = blockIdx.y * NB + blockIdx.x;
  const int xcd = f & 7;
  const int idx = f >> 3;
  const int m0 = (idx % MB) * 128;
  const int n0 = (xcd + (idx / MB) * 8) * 128;

  const int wm = (wid >> 1) * 64;
  const int wn = (wid & 1) * 64;
  const int Kc = K / SPLIT;
  const int kbase = blockIdx.z * Kc;
  const int nt = Kc / BK;

  f32x4_t acc[4][4];
  #pragma unroll
  for (int i = 0; i < 4; ++i)
    #pragma unroll
    for (int j = 0; j < 4; ++j) acc[i][j] = (f32x4_t){0.f, 0.f, 0.f, 0.f};

  // staging chunk c lands at LDS 16B-slot c (linear); it carries the data
  // for (row = c>>2, kc = (c&3) ^ ((row>>1)&3))  [T2 source-side swizzle]
  const int c1 = tid, c2 = tid + 256;
  const int r1c = c1 >> 2, r2c = c2 >> 2;
  const int kc1 = ((c1 & 3) ^ ((r1c >> 1) & 3)) * 8;
  const int kc2 = ((c2 & 3) ^ ((r2c >> 1) & 3)) * 8;
  const unsigned short* Ag1 = A + (size_t)(m0 + r1c) * K + kbase + kc1;
  const unsigned short* Ag2 = A + (size_t)(m0 + r2c) * K + kbase + kc2;
  const unsigned short* Wg1 = W + (size_t)(n0 + r1c) * K + kbase + kc1;
  const unsigned short* Wg2 = W + (size_t)(n0 + r2c) * K + kbase + kc2;
  const int l1 = c1 * 8, l2 = c2 * 8;

  auto stage = [&](int t, int b) {
    const int ko = t * BK;
    gl_lds16(Ag1 + ko, &As[b][l1]);
    gl_lds16(Ag2 + ko, &As[b][l2]);
    gl_lds16(Wg1 + ko, &Bs[b][l1]);
    gl_lds16(Wg2 + ko, &Bs[b][l2]);
  };
  auto compute = [&](int b) {
    bf16x8_t af[4], bfr[4];
    #pragma unroll
    for (int i = 0; i < 4; ++i) {
      const int row = wm + i * 16 + lrow;
      const int ch  = lq ^ ((row >> 1) & 3);
      af[i] = *(const bf16x8_t*)&As[b][row * BK + ch * 8];
    }
    #pragma unroll
    for (int j = 0; j < 4; ++j) {
      const int row = wn + j * 16 + lrow;
      const int ch  = lq ^ ((row >> 1) & 3);
      bfr[j] = *(const bf16x8_t*)&Bs[b][row * BK + ch * 8];
    }
    #pragma unroll
    for (int i = 0; i < 4; ++i)
      #pragma unroll
      for (int j = 0; j < 4; ++j)
        acc[i][j] = __builtin_amdgcn_mfma_f32_16x16x32_bf16(af[i], bfr[j], acc[i][j], 0, 0, 0);
  };

  // prologue: two tiles in flight
  stage(0, 0);
  stage(1, 1);

  int cr = 0;        // buffer being computed (t % 3)
  int cs = 2;        // buffer being staged ((t+2) % 3)
  for (int t = 0; t < nt - 1; ++t) {
    asm volatile("s_waitcnt vmcnt(4)" ::: "memory");  // tile t landed (per-wave)
    __builtin_amdgcn_sched_barrier(0);
    __builtin_amdgcn_s_barrier();                     // collective: buf[cr] ready
    __builtin_amdgcn_sched_barrier(0);
    if (t + 2 < nt) stage(t + 2, cs);
    compute(cr);
    cr = (cr == 2) ? 0 : cr + 1;
    cs = (cs == 2) ? 0 : cs + 1;
  }
  // last K-step: drain everything
  asm volatile("s_waitcnt vmcnt(0)" ::: "memory");
  __builtin_amdgcn_sched_barrier(0);
  __builtin_amdgcn_s_barrier();
  __builtin_amdgcn_sched_barrier(0);
  compute(cr);

  // epilogue
  float bj[4];
  #pragma unroll
  for (int j = 0; j < 4; ++j)
    bj[j] = (bias && (SPLIT == 1 || blockIdx.z == 0)) ? bias[n0 + wn + j * 16 + lrow] : 0.f;

  if (ROPE) {
    // wave-uniform: which qkv section + head for this 64-col strip
    const int strip = n0 + wn;
    const int which = strip >> 10;          // 0=q, 1=k, 2=v
    const int head  = (strip >> 6) & 15;
    #pragma unroll
    for (int i = 0; i < 4; ++i) {
      #pragma unroll
      for (int r = 0; r < 4; ++r) {
        const int row = m0 + wm + i * 16 + lq * 4 + r;   // row = s*2 + b
        const int s = row >> 1, b = row & 1;
        if (which == 2) {
          const size_t idx2 = (size_t)row * N + strip + lrow;
          #pragma unroll
          for (int j = 0; j < 4; ++j)
            ((unsigned short*)Cout)[idx2 + j * 16] = f2bf(acc[i][j][r] + bj[j]);
        } else {
          unsigned short* dst = (which == 0 ? qt : kt)
              + (((size_t)(b * 16 + head) * 1024 + s) << 6);
          #pragma unroll
          for (int j = 0; j < 4; ++j) {
            const int d = j * 16 + lrow;
            const float2 tt = trig[s * 32 + (d & 31)];
            const float sign = (j < 2) ? -1.0f : 1.0f;
            const float val = acc[i][j][r] + bj[j];
            const float par = acc[i][j ^ 2][r] + bj[j ^ 2];
            dst[d] = f2bf(val * tt.x + sign * par * tt.y);
          }
        }
      }
    }
  } else {
    // C/D layout col=lane&15, row=(lane>>4)*4+r
    const size_t zoff = PARTIAL ? (size_t)blockIdx.z * ((size_t)M * N) : 0;
    #pragma unroll
    for (int i = 0; i < 4; ++i) {
      #pragma unroll
      for (int r = 0; r < 4; ++r) {
        const int row = m0 + wm + i * 16 + lq * 4 + r;
        const size_t idx2 = (size_t)row * N + n0 + wn + lrow;
        #pragma unroll
        for (int j = 0; j < 4; ++j) {
          float val = acc[i][j][r] + bj[j];
          if (GELU)
            val = 0.5f * val * (1.0f + erff(val * 0.70710678118654752f));
          if (PARTIAL)
            ((float*)Cout)[zoff + idx2 + j * 16] = val;
          else if (OUTBF16)
            ((unsigned short*)Cout)[idx2 + j * 16] = f2bf(val);
          else
            ((float*)Cout)[idx2 + j * 16] = val;
        }
      }
    }
  }
}

// ---------------------------------------------------------------------------
// V transpose via LDS tile: qkv v-part (s-major) -> vt (B,H,64,S) d-major.
// ---------------------------------------------------------------------------
__global__ __launch_bounds__(256) void vtrans_kernel(const unsigned short* __restrict__ qkv,
    unsigned short* __restrict__ vt) {
  const int bh = blockIdx.x >> 4;
  const int s0 = (blockIdx.x & 15) * 64;
  const int b = bh >> 4, hh = bh & 15;
  __shared__ unsigned short Vl[64 * 72];
  const int t = threadIdx.x;
  const int sl = t >> 2, dcol = (t & 3) * 16;
  const unsigned short* src = qkv + (size_t)((s0 + sl) * 2 + b) * 3072 + 2048 + hh * 64 + dcol;
  uint4 a = *(const uint4*)(src);
  uint4 c = *(const uint4*)(src + 8);
  *(uint4*)&Vl[sl * 72 + dcol]     = a;
  *(uint4*)&Vl[sl * 72 + dcol + 8] = c;
  __syncthreads();
  const int dr = t >> 2, soff = (t & 3) * 16;
  unsigned short o[16];
  #pragma unroll
  for (int i = 0; i < 16; ++i) o[i] = Vl[(soff + i) * 72 + dr];
  unsigned short* dst = vt + (((size_t)bh * 64 + dr) << 10) + s0 + soff;
  *(uint4*)(dst)     = *(uint4*)(o);
  *(uint4*)(dst + 8) = *(uint4*)(o + 8);
}

// ---------------------------------------------------------------------------
// MFMA flash attention v3: 8-wave 512-thread blocks, in-block KV-split x2.
// Waves 0-3 (half 0) process queries 0-63 over KV[0,512); waves 4-7 (half 1)
// same queries over KV[512,1024). Each wave's serial tile chain halves
// (8 tiles), waves/CU doubles (16), staging per thread stays the proven
// 2+2 uint4 (r11's 8-uint4 version spilled to scratch: WRITE_SIZE 199MB).
// Halves merge through an LDS overlay at the end — no global merge traffic.
// ---------------------------------------------------------------------------
__global__ __launch_bounds__(512, 4) void attn_kernel(
    const unsigned short* __restrict__ q, const unsigned short* __restrict__ k,
    const unsigned short* __restrict__ vtr, unsigned short* __restrict__ o) {
  const int tid  = threadIdx.x;
  const int wid  = tid >> 6;          // 0..7
  const int qg   = wid & 3;           // q-group
  const int half = tid >> 8;          // KV half (== wid>>2)
  const int lane = tid & 63;
  const int col  = lane & 15;
  const int quad = lane >> 4;
  const int bh   = blockIdx.x >> 4;
  const int qw   = (blockIdx.x & 15) * 64 + qg * 16;
  const int tbase = half * 512;

  __shared__ __align__(16) unsigned short Ks[2][64 * 72];
  __shared__ __align__(16) unsigned short Vs[2][64 * 72];
  __shared__ __align__(16) unsigned short Pl_[8][16 * 72];
  unsigned short* Pl = Pl_[wid];

  const unsigned short* kb = k   + ((size_t)bh << 16);
  const unsigned short* vb = vtr + ((size_t)bh << 16);

  bf16x8_t qa0, qa1;
  {
    const unsigned short* qp = q + ((((size_t)bh << 10) + qw + col) << 6) + quad * 8;
    qa0 = *(const bf16x8_t*)(qp);
    qa1 = *(const bf16x8_t*)(qp + 32);
  }

  f32x4_t oacc[4];
  #pragma unroll
  for (int j = 0; j < 4; ++j) oacc[j] = (f32x4_t){0.f, 0.f, 0.f, 0.f};
  float mr[4] = {-3.0e38f, -3.0e38f, -3.0e38f, -3.0e38f};
  float lr[4] = {0.f, 0.f, 0.f, 0.f};

  // staging: each 256-thread half stages its own Ks/Vs buffer (32B K + 32B V
  // per thread = 2+2 uint4, the known no-spill shape)
  const int ht   = tid & 255;
  const int srow = ht >> 2;
  const int scol = (ht & 3) * 16;
  const unsigned short* gk0 = kb + (size_t)(tbase + srow) * 64 + scol;
  const unsigned short* gv0 = vb + (size_t)srow * 1024 + tbase + scol;
  unsigned short* lk0 = &Ks[half][srow * 72 + scol];
  unsigned short* lv0 = &Vs[half][srow * 72 + scol];

  // prologue: stage tile 0 of this half
  {
    uint4 ka = *(const uint4*)(gk0);
    uint4 kc = *(const uint4*)(gk0 + 8);
    uint4 va = *(const uint4*)(gv0);
    uint4 vc = *(const uint4*)(gv0 + 8);
    *(uint4*)(lk0)     = ka;
    *(uint4*)(lk0 + 8) = kc;
    *(uint4*)(lv0)     = va;
    *(uint4*)(lv0 + 8) = vc;
  }
  __syncthreads();

  for (int t0 = 0; t0 < 512; t0 += 64) {
    // T14 issue-early: next tile's loads go in flight during compute
    const bool more = (t0 + 64) < 512;
    uint4 nka, nkc, nva, nvc;
    if (more) {
      const unsigned short* gk = gk0 + (size_t)(t0 + 64) * 64;
      const unsigned short* gv = gv0 + (t0 + 64);
      nka = *(const uint4*)(gk);
      nkc = *(const uint4*)(gk + 8);
      nva = *(const uint4*)(gv);
      nvc = *(const uint4*)(gv + 8);
    }

    f32x4_t sc[4];
    #pragma unroll
    for (int j = 0; j < 4; ++j) {
      bf16x8_t kf0 = *(const bf16x8_t*)&Ks[half][(j * 16 + col) * 72 + quad * 8];
      bf16x8_t kf1 = *(const bf16x8_t*)&Ks[half][(j * 16 + col) * 72 + quad * 8 + 32];
      f32x4_t c = (f32x4_t){0.f, 0.f, 0.f, 0.f};
      c = __builtin_amdgcn_mfma_f32_16x16x32_bf16(qa0, kf0, c, 0, 0, 0);
      c = __builtin_amdgcn_mfma_f32_16x16x32_bf16(qa1, kf1, c, 0, 0, 0);
      sc[j] = c;
    }

    #pragma unroll
    for (int r = 0; r < 4; ++r) {
      float s0 = sc[0][r] * 0.125f, s1 = sc[1][r] * 0.125f;
      float s2 = sc[2][r] * 0.125f, s3 = sc[3][r] * 0.125f;
      const float rm = rowmax16(fmaxf(fmaxf(s0, s1), fmaxf(s2, s3)));
      if (__any(rm > mr[r])) {              // exact: alpha==1 when skipped
        const float mn = fmaxf(mr[r], rm);
        const float alpha = __expf(mr[r] - mn);
        mr[r] = mn;
        lr[r] *= alpha;
        #pragma unroll
        for (int j = 0; j < 4; ++j) oacc[j][r] *= alpha;
      }
      const float m = mr[r];
      const float p0 = __expf(s0 - m), p1 = __expf(s1 - m);
      const float p2 = __expf(s2 - m), p3 = __expf(s3 - m);
      lr[r] += rowsum16(p0 + p1 + p2 + p3);
      const int prow = (quad * 4 + r) * 72;
      Pl[prow +  0 + col] = f2bf(p0);
      Pl[prow + 16 + col] = f2bf(p1);
      Pl[prow + 32 + col] = f2bf(p2);
      Pl[prow + 48 + col] = f2bf(p3);
    }

    bf16x8_t pa0 = *(const bf16x8_t*)&Pl[col * 72 + quad * 8];
    bf16x8_t pa1 = *(const bf16x8_t*)&Pl[col * 72 + quad * 8 + 32];
    #pragma unroll
    for (int j = 0; j < 4; ++j) {
      bf16x8_t vf0 = *(const bf16x8_t*)&Vs[half][(j * 16 + col) * 72 + quad * 8];
      bf16x8_t vf1 = *(const bf16x8_t*)&Vs[half][(j * 16 + col) * 72 + quad * 8 + 32];
      oacc[j] = __builtin_amdgcn_mfma_f32_16x16x32_bf16(pa0, vf0, oacc[j], 0, 0, 0);
      oacc[j] = __builtin_amdgcn_mfma_f32_16x16x32_bf16(pa1, vf1, oacc[j], 0, 0, 0);
    }

    // write-late: all waves done reading Ks/Vs, then land the staged regs
    __syncthreads();
    if (more) {
      *(uint4*)(lk0)     = nka;
      *(uint4*)(lk0 + 8) = nkc;
      *(uint4*)(lv0)     = nva;
      *(uint4*)(lv0 + 8) = nvc;
    }
    __syncthreads();
  }

  // ---- merge the two halves through LDS (overlay on dead K buffers) ----
  float* sm = (float*)Ks;   // 4608 floats available; need 4*16*68 = 4352
  __syncthreads();
  if (half == 1) {
    #pragma unroll
    for (int r = 0; r < 4; ++r) {
      const int ro = quad * 4 + r;
      float* row = sm + (size_t)(qg * 16 + ro) * 68;
      #pragma unroll
      for (int j = 0; j < 4; ++j) row[j * 16 + col] = oacc[j][r];
      if (col == 0) { row[64] = mr[r]; row[65] = lr[r]; }
    }
  }
  __syncthreads();
  if (half == 0) {
    const int b = bh >> 4, hh = bh & 15;
    #pragma unroll
    for (int r = 0; r < 4; ++r) {
      const int ro = quad * 4 + r;
      const float* row = sm + (size_t)(qg * 16 + ro) * 68;
      const float m1 = row[64], l1 = row[65];
      const float M = fmaxf(mr[r], m1);
      const float e0 = __expf(mr[r] - M), e1 = __expf(m1 - M);
      const float inv = 1.0f / (e0 * lr[r] + e1 * l1);
      const int sq = qw + ro;
      unsigned short* orow = o + (((size_t)sq * 2 + b) << 10) + hh * 64;
      #pragma unroll
      for (int j = 0; j < 4; ++j)
        orow[j * 16 + col] = f2bf((oacc[j][r] * e0 + row[j * 16 + col] * e1) * inv);
    }
  }
}

// ---------------------------------------------------------------------------
// Mean over tokens: tsum[b,d] += sum_s h[s,b,d] (8 s-chunks, atomicAdd).
// ---------------------------------------------------------------------------
__global__ __launch_bounds__(256) void mean_kernel(const float* __restrict__ h,
    float* __restrict__ tsum) {
  const int idx = blockIdx.x * 256 + threadIdx.x;
  const int bd = idx & 2047;
  const int sc = idx >> 11;
  const int b = bd >> 10, d = bd & 1023;
  float sm = 0.f;
  for (int s = sc * 128; s < sc * 128 + 128; ++s)
    sm += h[(((size_t)s * 2 + b) << 10) + d];
  atomicAdd(&tsum[bd], sm);
}

// ---------------------------------------------------------------------------
// Small mat-vec: out[b,n] = sum_d in[b,d]*W[n,d] (+bias). Wave per output n.
// ---------------------------------------------------------------------------
__global__ __launch_bounds__(256) void smallmv_kernel(const float* __restrict__ in,
    const float* __restrict__ W, const float* __restrict__ bias,
    float* __restrict__ out) {
  const int lane = threadIdx.x & 63;
  const int n = blockIdx.x * 4 + (threadIdx.x >> 6);
  const int b = blockIdx.y;
  const float* wr = W + (size_t)n * 1024;
  const float* xr = in + (size_t)b * 1024;
  float sm = 0.f;
  #pragma unroll
  for (int j = 0; j < 4; ++j) {
    float4 wv = *(const float4*)(wr + lane * 4 + j * 256);
    float4 xv = *(const float4*)(xr + lane * 4 + j * 256);
    sm += wv.x * xv.x + wv.y * xv.y + wv.z * xv.z + wv.w * xv.w;
  }
  #pragma unroll
  for (int off = 32; off; off >>= 1) sm += __shfl_xor(sm, off);
  if (lane == 0) out[(size_t)b * 1024 + n] = sm + (bias ? bias[n] : 0.f);
}

// ---------------------------------------------------------------------------
// Pooling cross-attention, split-K: 512 waves, each (bh, 64-key block).
// ---------------------------------------------------------------------------
__global__ __launch_bounds__(256) void pool_attn_part(const float* __restrict__ q,
    const float* __restrict__ k, const float* __restrict__ v,
    float* __restrict__ part) {
  const int wid  = (blockIdx.x * 256 + threadIdx.x) >> 6;  // 0..511
  const int lane = threadIdx.x & 63;
  const int bh = wid >> 4, kblk = wid & 15;
  const int b = bh >> 4, hh = bh & 15;
  const float qd = q[(size_t)b * 1024 + hh * 64 + lane];
  float mx = -3.0e38f, l = 0.f, acc = 0.f;
  for (int t = kblk * 64; t < kblk * 64 + 64; ++t) {
    const size_t ro = (((size_t)t * 2 + b) << 10) + hh * 64 + lane;
    float p = qd * k[ro];
    p += __shfl_xor(p, 32); p += __shfl_xor(p, 16); p += __shfl_xor(p, 8);
    p += __shfl_xor(p, 4);  p += __shfl_xor(p, 2);  p += __shfl_xor(p, 1);
    const float sc = p * 0.125f;
    const float mn = fmaxf(mx, sc);
    const float alpha = __expf(mx - mn);
    const float w = __expf(sc - mn);
    acc = acc * alpha + w * v[ro];
    l   = l * alpha + w;
    mx  = mn;
  }
  float* pp = part + (size_t)wid * 68;
  if (lane == 0) { pp[0] = mx; pp[1] = l; }
  pp[4 + lane] = acc;
}

__global__ __launch_bounds__(256) void pool_attn_comb(const float* __restrict__ part,
    float* __restrict__ o) {
  const int wid  = (blockIdx.x * 256 + threadIdx.x) >> 6;  // 0..31 = bh
  const int lane = threadIdx.x & 63;
  const float* pb = part + (size_t)wid * 16 * 68;
  float M = -3.0e38f;
  #pragma unroll
  for (int w = 0; w < 16; ++w) M = fmaxf(M, pb[w * 68]);
  float L = 0.f, O = 0.f;
  #pragma unroll
  for (int w = 0; w < 16; ++w) {
    const float e = __expf(pb[w * 68] - M);
    L += e * pb[w * 68 + 1];
    O += e * pb[w * 68 + 4 + lane];
  }
  const int b = wid >> 4, hh = wid & 15;
  o[(size_t)b * 1024 + hh * 64 + lane] = O / L;
}

// ---------------------------------------------------------------------------
extern "C" void kernel_launch(void* const* d_in, const int* in_sizes, int n_in,
                              void* d_out, int out_size, void* d_ws, size_t ws_size,
                              hipStream_t stream) {
  (void)in_sizes; (void)n_in; (void)out_size; (void)ws_size;
  const float* x     = (const float*)d_in[0];
  const float* rot   = (const float*)d_in[1];
  const float* ln1_w = (const float*)d_in[2];
  const float* ln1_b = (const float*)d_in[3];
  const float* in_w  = (const float*)d_in[4];
  const float* in_b  = (const float*)d_in[5];
  const float* out_w = (const float*)d_in[6];
  const float* out_b = (const float*)d_in[7];
  const float* ln2_w = (const float*)d_in[8];
  const float* ln2_b = (const float*)d_in[9];
  const float* fc_w  = (const float*)d_in[10];
  const float* fc_b  = (const float*)d_in[11];
  const float* cp_w  = (const float*)d_in[12];
  const float* cp_b  = (const float*)d_in[13];
  const float* pn_q_w = (const float*)d_in[14];
  const float* pn_q_b = (const float*)d_in[15];
  const float* pn_k_w = (const float*)d_in[16];
  const float* pn_k_b = (const float*)d_in[17];
  const float* pn_v_w = (const float*)d_in[18];
  const float* pn_v_b = (const float*)d_in[19];
  const float* pq_w  = (const float*)d_in[20];
  const float* pk_w  = (const float*)d_in[21];
  const float* pv_w  = (const float*)d_in[22];
  const float* pp_w  = (const float*)d_in[23];
  const float* pp_b  = (const float*)d_in[24];

  float* ws = (float*)d_ws;
  const size_t M1 = 1u << 20;
  float* h  = ws;              // 2M fl  (S,B,D) residual stream fp32
  float* a  = ws + 2 * M1;     // LN out bf16 / xk bf16
  float* r1 = ws + 4 * M1;     // qkv(v) bf16 / mlp bf16 / xv bf16; out-proj partials
  float* qt = ws + 12 * M1;    // q bf16 (B,H,S,64)  | c_proj partials | pooling scratch
  float* kt = ws + 14 * M1;    // k bf16 (B,H,S,64)  | k_pool fp32
  float* vt = ws + 16 * M1;    // v^T bf16 (B,H,64,S)| v_pool fp32
  float* o  = ws + 18 * M1;    // attn out bf16 (S,B,D)
  float* trig = ws + 19 * M1;  // 32K float2 cos/sin table (64K floats)
  float* wbf = ws + 20 * M1;   // bf16 weights, ALL layers
  unsigned short* a_bf  = (unsigned short*)a;
  unsigned short* r1_bf = (unsigned short*)r1;
  unsigned short* o_bf  = (unsigned short*)o;
  unsigned short* qt_bf = (unsigned short*)qt;
  unsigned short* kt_bf = (unsigned short*)kt;
  unsigned short* vt_bf = (unsigned short*)vt;
  // bf16 weight partitions, all 4 layers (ushort elems)
  unsigned short* wb_qkv_all = (unsigned short*)wbf;        // 12,582,912
  unsigned short* wb_out_all = wb_qkv_all + 12582912;       //  4,194,304
  unsigned short* wb_fc_all  = wb_out_all + 4194304;        // 16,777,216
  unsigned short* wb_cp_all  = wb_fc_all  + 16777216;       // 16,777,216
  // split-K partial buffers (fp32, slice stride MROWS*DMODEL = 2M floats)
  float* part_op = r1;            // out-proj partials (4 x 2M1)
  float* part_cp = qt;            // c_proj partials (4 x 2M1)
  float* part_pool = ws + 5 * M1; // pool partials SPLIT=2 (2 x 2M1)
  float* tsum  = qt;              // pooling scratch reuses qt region
  float* xq    = qt + 2048;
  float* qpool = qt + 4096;
  float* opool = qt + 6144;
  float* ppart = qt + 8192;       // 512*68 floats

  hipMemcpyAsync(h, x, 2 * M1 * sizeof(float), hipMemcpyDeviceToDevice, stream);

  // one-time setup: trig table, ln1 for layer 0, ALL weight conversions
  trig_kernel<<<128, 256, 0, stream>>>(rot, (float2*)trig);
  ln_kernel<true><<<MROWS, 256, 0, stream>>>(h, ln1_w, ln1_b, a_bf, 1.0f);
  w2bf_kernel<<<12582912 / 2048, 256, 0, stream>>>(in_w,  wb_qkv_all, 12582912);
  w2bf_kernel<<<4194304  / 2048, 256, 0, stream>>>(out_w, wb_out_all, 4194304);
  w2bf_kernel<<<16777216 / 2048, 256, 0, stream>>>(fc_w,  wb_fc_all,  16777216);
  w2bf_kernel<<<16777216 / 2048, 256, 0, stream>>>(cp_w,  wb_cp_all,  16777216);

  for (int l = 0; l < NLAYER; ++l) {
    const unsigned short* wb_qkv = wb_qkv_all + (size_t)l * 3145728;
    const unsigned short* wb_out = wb_out_all + (size_t)l * 1048576;
    const unsigned short* wb_fc  = wb_fc_all  + (size_t)l * 4194304;
    const unsigned short* wb_cp  = wb_cp_all  + (size_t)l * 4194304;

    // QKV with FUSED RoPE epilogue: q/k -> qt/kt (rotated), v -> r1
    gemm_mfma<1, false, false, true, true><<<dim3(3072 / 128, MROWS / 128, 1), 256, 0, stream>>>(
        a_bf, wb_qkv, in_b + l * 3072, r1_bf, MROWS, 3072, 1024,
        (const float2*)trig, qt_bf, kt_bf);
    vtrans_kernel<<<512, 256, 0, stream>>>(r1_bf, vt_bf);
    attn_kernel<<<512, 512, 0, stream>>>(qt_bf, kt_bf, vt_bf, o_bf);
    // out-proj: SPLIT=4 partials (no atomics), then reduce + residual + ln2
    gemm_mfma<4, false, true, false, false><<<dim3(1024 / 128, MROWS / 128, 4), 256, 0, stream>>>(
        o_bf, wb_out, nullptr, part_op, MROWS, 1024, 1024, nullptr, nullptr, nullptr);
    reduce_ln_kernel<4, true, true><<<MROWS, 256, 0, stream>>>(
        part_op, out_b + l * 1024, h, ln2_w + l * DMODEL, ln2_b + l * DMODEL, a_bf);
    // FC + GELU: SPLIT=1, bf16 out
    gemm_mfma<1, true, false, true, false><<<dim3(4096 / 128, MROWS / 128, 1), 256, 0, stream>>>(
        a_bf, wb_fc, fc_b + l * 4096, r1_bf, MROWS, 4096, 1024, nullptr, nullptr, nullptr);
    // c_proj: SPLIT=4 partials, then reduce + residual + next layer's ln1
    gemm_mfma<4, false, true, false, false><<<dim3(1024 / 128, MROWS / 128, 4), 256, 0, stream>>>(
        r1_bf, wb_cp, nullptr, part_cp, MROWS, 1024, 4096, nullptr, nullptr, nullptr);
    if (l < NLAYER - 1)
      reduce_ln_kernel<4, true, true><<<MROWS, 256, 0, stream>>>(
          part_cp, cp_b + l * 1024, h,
          ln1_w + (l + 1) * DMODEL, ln1_b + (l + 1) * DMODEL, a_bf);
    else
      reduce_ln_kernel<4, true, false><<<MROWS, 256, 0, stream>>>(
          part_cp, cp_b + l * 1024, h, nullptr, nullptr, nullptr);
  }

  // ---- attention pooling head ----
  hipMemsetAsync(tsum, 0, 2048 * sizeof(float), stream);
  mean_kernel<<<64, 256, 0, stream>>>(h, tsum);
  ln_kernel<false><<<BATCH, 256, 0, stream>>>(tsum, pn_q_w, pn_q_b, xq, 1.0f / S_LEN);
  ln_kernel<true><<<MROWS, 256, 0, stream>>>(h, pn_k_w, pn_k_b, a_bf, 1.0f);    // xk bf16
  ln_kernel<true><<<MROWS, 256, 0, stream>>>(h, pn_v_w, pn_v_b, r1_bf, 1.0f);   // xv bf16
  smallmv_kernel<<<dim3(256, BATCH), 256, 0, stream>>>(xq, pq_w, nullptr, qpool);
  // pool k/v projections: bf16 weights (reuse weight region), SPLIT=2 partials
  unsigned short* wb_pk = wb_qkv_all;
  unsigned short* wb_pv = wb_qkv_all + 1048576;
  w2bf_kernel<<<1048576 / 2048, 256, 0, stream>>>(pk_w, wb_pk, 1048576);
  w2bf_kernel<<<1048576 / 2048, 256, 0, stream>>>(pv_w, wb_pv, 1048576);
  gemm_mfma<2, false, true, false, false><<<dim3(1024 / 128, MROWS / 128, 2), 256, 0, stream>>>(
      a_bf, wb_pk, nullptr, part_pool, MROWS, 1024, 1024, nullptr, nullptr, nullptr);
  reduce_ln_kernel<2, false, false><<<MROWS, 256, 0, stream>>>(
      part_pool, nullptr, kt, nullptr, nullptr, nullptr);   // k_pool fp32
  gemm_mfma<2, false, true, false, false><<<dim3(1024 / 128, MROWS / 128, 2), 256, 0, stream>>>(
      r1_bf, wb_pv, nullptr, part_pool, MROWS, 1024, 1024, nullptr, nullptr, nullptr);
  reduce_ln_kernel<2, false, false><<<MROWS, 256, 0, stream>>>(
      part_pool, nullptr, vt, nullptr, nullptr, nullptr);   // v_pool fp32
  pool_attn_part<<<128, 256, 0, stream>>>(qpool, kt, vt, ppart);
  pool_attn_comb<<<8, 256, 0, stream>>>(ppart, opool);
  smallmv_kernel<<<dim3(256, BATCH), 256, 0, stream>>>(opool, pp_w, pp_b, (float*)d_out);
}